// Round 1
// baseline (1427.788 us; speedup 1.0000x reference)
//
#include <hip/hip_runtime.h>
#include <cstdint>

#define NPTS 8192
#define NB 8
#define DS 512
#define CF 64
#define KNN 32

__device__ __forceinline__ unsigned long long shxor_u64(unsigned long long v, int o) {
  return __shfl_xor(v, o, 64);
}

__global__ __launch_bounds__(64) void zero_kernel(float* __restrict__ acc) {
  if (threadIdx.x < 16) acc[threadIdx.x] = 0.0f;
}

// blocks 0..15: FPS (view=blk>>3, batch=blk&7). blocks 16..79: global cosine loss.
__global__ __launch_bounds__(1024) void fps_cos_kernel(
    const float* __restrict__ logits, const float* __restrict__ logits1,
    const float* __restrict__ p0first, const float* __restrict__ p0sec,
    int* __restrict__ idxbuf, float* __restrict__ acc) {
  __shared__ unsigned long long redk[16];
  __shared__ float4 redc[16];
  __shared__ float4 winf4;
  __shared__ float s_sum;
  const int blk = blockIdx.x;
  const int t = threadIdx.x;
  if (blk < 16) {
    const int view = blk >> 3, b = blk & 7;
    const float* p = (view ? p0sec : p0first) + (size_t)b * NPTS * 3;
    int* idx_out = idxbuf + blk * DS;
    float px[8], py[8], pz[8], dist[8];
#pragma unroll
    for (int j = 0; j < 8; ++j) {
      int e = j * 1024 + t;
      px[j] = p[e * 3 + 0];
      py[j] = p[e * 3 + 1];
      pz[j] = p[e * 3 + 2];
    }
    float wx = p[0], wy = p[1], wz = p[2];  // seed = point 0
    float bv = -1.0f, bx = 0.f, by = 0.f, bz = 0.f;
    int be = 0;
#pragma unroll
    for (int j = 0; j < 8; ++j) {
      float dx = px[j] - wx, dy = py[j] - wy, dz = pz[j] - wz;
      float d = dx * dx + dy * dy + dz * dz;
      dist[j] = d;
      if (d > bv) { bv = d; be = j * 1024 + t; bx = px[j]; by = py[j]; bz = pz[j]; }
    }
    if (t == 0) idx_out[0] = 0;
    const int wave = t >> 6, lane = t & 63;
    for (int it = 1; it < DS; ++it) {
      // key: max dist wins; equal dist -> smaller element index (matches jnp.argmax)
      unsigned long long key =
          (((unsigned long long)__float_as_uint(bv)) << 32) | (unsigned)(8191 - be);
      float cx = bx, cy = by, cz = bz;
#pragma unroll
      for (int o = 32; o; o >>= 1) {
        unsigned long long ok = shxor_u64(key, o);
        float ox = __shfl_xor(cx, o, 64);
        float oy = __shfl_xor(cy, o, 64);
        float oz = __shfl_xor(cz, o, 64);
        if (ok > key) { key = ok; cx = ox; cy = oy; cz = oz; }
      }
      if (lane == 0) { redk[wave] = key; redc[wave] = make_float4(cx, cy, cz, 0.0f); }
      __syncthreads();
      if (wave == 0) {
        unsigned long long k2 = redk[lane & 15];
        float4 c2 = redc[lane & 15];
#pragma unroll
        for (int o = 8; o; o >>= 1) {
          unsigned long long ok = shxor_u64(k2, o);
          float ox = __shfl_xor(c2.x, o, 64);
          float oy = __shfl_xor(c2.y, o, 64);
          float oz = __shfl_xor(c2.z, o, 64);
          if (ok > k2) { k2 = ok; c2.x = ox; c2.y = oy; c2.z = oz; }
        }
        if (lane == 0) {
          int e = 8191 - (int)(k2 & 0xffffffffu);
          winf4 = make_float4(c2.x, c2.y, c2.z, __int_as_float(e));
        }
      }
      __syncthreads();
      float4 w4 = winf4;
      wx = w4.x; wy = w4.y; wz = w4.z;
      int e = __float_as_int(w4.w);
      if (t == 0) idx_out[it] = e;
      bv = -1.0f;
#pragma unroll
      for (int j = 0; j < 8; ++j) {
        float dx = px[j] - wx, dy = py[j] - wy, dz = pz[j] - wz;
        float nd = dx * dx + dy * dy + dz * dz;
        float d = fminf(dist[j], nd);
        dist[j] = d;
        if (d > bv) { bv = d; be = j * 1024 + t; bx = px[j]; by = py[j]; bz = pz[j]; }
      }
    }
  } else {
    // global per-point cosine loss: one thread per row of 64
    if (t == 0) s_sum = 0.0f;
    __syncthreads();
    const int row = (blk - 16) * 1024 + t;  // 0..65535
    const float4* A = (const float4*)(logits + (size_t)row * CF);
    const float4* Bv = (const float4*)(logits1 + (size_t)row * CF);
    float ab = 0.f, aa = 0.f, bb = 0.f;
#pragma unroll
    for (int i = 0; i < 16; ++i) {
      float4 a = A[i], c = Bv[i];
      ab += a.x * c.x + a.y * c.y + a.z * c.z + a.w * c.w;
      aa += a.x * a.x + a.y * a.y + a.z * a.z + a.w * a.w;
      bb += c.x * c.x + c.y * c.y + c.z * c.z + c.w * c.w;
    }
    float cv = ab / fmaxf(sqrtf(aa) * sqrtf(bb), 1e-8f);
#pragma unroll
    for (int o = 32; o; o >>= 1) cv += __shfl_xor(cv, o, 64);
    if ((t & 63) == 0) atomicAdd(&s_sum, cv);
    __syncthreads();
    if (t == 0) atomicAdd(&acc[0], s_sum);
  }
}

// scan 256-bin LDS histogram, pick bin containing rrank; s_bl[0]=bin, s_bl[1]=count below bin
__device__ __forceinline__ void radix_scan(int* hist, int rrank, int* s_bl, int t) {
  if (t < 64) {
    int h0 = hist[t * 4 + 0], h1 = hist[t * 4 + 1], h2 = hist[t * 4 + 2], h3 = hist[t * 4 + 3];
    int s = h0 + h1 + h2 + h3;
    int inc = s;
#pragma unroll
    for (int o = 1; o < 64; o <<= 1) {
      int v = __shfl_up(inc, o, 64);
      if (t >= o) inc += v;
    }
    int exc = inc - s;
    bool has = (rrank >= exc) && (rrank < inc);
    unsigned long long mask = __ballot(has);
    int win = __ffsll(mask) - 1;
    int wexc = __shfl(exc, win, 64);
    int wh0 = __shfl(h0, win, 64), wh1 = __shfl(h1, win, 64);
    int wh2 = __shfl(h2, win, 64), wh3 = __shfl(h3, win, 64);
    (void)wh3;
    int r2 = rrank - wexc;
    int bin, less;
    if (r2 < wh0) { bin = 0; less = 0; }
    else if (r2 < wh0 + wh1) { bin = 1; less = wh0; }
    else if (r2 < wh0 + wh1 + wh2) { bin = 2; less = wh0 + wh1; }
    else { bin = 3; less = wh0 + wh1 + wh2; }
    if (t == 0) { s_bl[0] = win * 4 + bin; s_bl[1] = wexc + less; }
  }
  __syncthreads();
}

// one block (256 thr) per query; exact top-32 set via 4-pass radix select on sortable keys
__global__ __launch_bounds__(256) void knn_kernel(
    const float* __restrict__ p0first, const float* __restrict__ p0sec,
    const int* __restrict__ idxbuf, int* __restrict__ knnbuf) {
  __shared__ int hist[256];
  __shared__ int s_bl[2];
  __shared__ int ctr, eqctr;
  __shared__ int eq[256];
  const int g = blockIdx.x;  // 0..8191 : view*4096 + b*512 + m
  const int t = threadIdx.x;
  const int view = g >> 12, b = (g >> 9) & 7;
  const float* p = (view ? p0sec : p0first) + (size_t)b * NPTS * 3;
  const int qi = idxbuf[g];
  const float qx = p[qi * 3], qy = p[qi * 3 + 1], qz = p[qi * 3 + 2];
  const float qq = qx * qx + qy * qy + qz * qz;
  unsigned sk[32];
#pragma unroll
  for (int j = 0; j < 32; ++j) {
    int e = j * 256 + t;
    float sx = p[e * 3], sy = p[e * 3 + 1], sz = p[e * 3 + 2];
    float ss = sx * sx + sy * sy + sz * sz;
    float dt = qx * sx + qy * sy + qz * sz;
    float d = qq + ss - 2.0f * dt;  // same formula as reference
    unsigned u = __float_as_uint(d);
    u = (u & 0x80000000u) ? ~u : (u | 0x80000000u);  // sortable
    sk[j] = u;
  }
  int rrank = 31;  // 0-indexed rank of 32nd smallest
  unsigned prefix = 0;
  // pass 0
  hist[t] = 0;
  __syncthreads();
#pragma unroll
  for (int j = 0; j < 32; ++j) atomicAdd(&hist[sk[j] >> 24], 1);
  __syncthreads();
  radix_scan(hist, rrank, s_bl, t);
  prefix = (unsigned)s_bl[0];
  rrank -= s_bl[1];
  // passes 1..3
  for (int pass = 1; pass < 4; ++pass) {
    const int shift = 24 - pass * 8;
    hist[t] = 0;
    __syncthreads();
#pragma unroll
    for (int j = 0; j < 32; ++j) {
      unsigned u = sk[j];
      if ((u >> (shift + 8)) == prefix) atomicAdd(&hist[(u >> shift) & 255], 1);
    }
    __syncthreads();
    radix_scan(hist, rrank, s_bl, t);
    prefix = (prefix << 8) | (unsigned)s_bl[0];
    rrank -= s_bl[1];
  }
  // output: all keys < V, plus (rrank+1) smallest-index keys == V. Order irrelevant.
  if (t == 0) { ctr = 0; eqctr = 0; }
  __syncthreads();
  const unsigned V = prefix;
  int* out = knnbuf + (size_t)g * KNN;
#pragma unroll
  for (int j = 0; j < 32; ++j) {
    unsigned u = sk[j];
    if (u < V) {
      int s = atomicAdd(&ctr, 1);
      out[s] = j * 256 + t;
    } else if (u == V) {
      int s2 = atomicAdd(&eqctr, 1);
      if (s2 < 256) eq[s2] = j * 256 + t;
    }
  }
  __syncthreads();
  if (t == 0) {
    int need = rrank + 1;
    int E = eqctr; if (E > 256) E = 256;
    int base = 32 - need;
    for (int s = 0; s < need; ++s) {
      int mi = 0;
      for (int i = 1; i < E; ++i)
        if (eq[i] < eq[mi]) mi = i;
      out[base + s] = eq[mi];
      eq[mi] = 0x7fffffff;
    }
  }
}

// one wave per group (lane = feature dim); 4 groups per block
__global__ __launch_bounds__(256) void group_kernel(
    const float* __restrict__ logits, const float* __restrict__ logits1,
    const int* __restrict__ idxbuf, const int* __restrict__ knnbuf,
    float* __restrict__ acc) {
  __shared__ float ws4[4];
  const int w = threadIdx.x >> 6, lane = threadIdx.x & 63;
  const int wid = blockIdx.x * 4 + w;  // 0..8191
  const int view = wid >> 12, b = (wid >> 9) & 7;
  const float* f = (view ? logits1 : logits) + (size_t)b * NPTS * CF;
  const int* nb = knnbuf + (size_t)wid * KNN;
  const int ci = idxbuf[wid];
  float r[33];
  float avg = 0.0f;
#pragma unroll
  for (int j = 0; j < 33; ++j) {
    int e = (j < 32) ? nb[j] : ci;
    float v = f[(size_t)e * CF + lane];
    r[j] = v;
    avg += v;
  }
  avg *= (1.0f / 33.0f);
  float na = avg * avg;
#pragma unroll
  for (int o = 32; o; o >>= 1) na += __shfl_xor(na, o, 64);
  const float rsna = sqrtf(na);
  float loss = 0.0f;
#pragma unroll
  for (int j = 0; j < 33; ++j) {
    float d0 = r[j] * avg, n0 = r[j] * r[j];
#pragma unroll
    for (int o = 32; o; o >>= 1) {
      d0 += __shfl_xor(d0, o, 64);
      n0 += __shfl_xor(n0, o, 64);
    }
    float den = fmaxf(sqrtf(n0) * rsna, 1e-8f);
    loss += -200.0f * (d0 / den) - 0.5f * log1pf(40.0f * n0);
  }
  loss *= (1.0f / 33.0f);
  if (lane == 0) ws4[w] = loss;
  __syncthreads();
  if (threadIdx.x == 0) atomicAdd(&acc[1 + b], ws4[0] + ws4[1] + ws4[2] + ws4[3]);
}

__global__ __launch_bounds__(64) void finalize_kernel(const float* __restrict__ acc,
                                                      float* __restrict__ out) {
  if (threadIdx.x == 0 && blockIdx.x == 0) {
    float gl = -acc[0] / 65536.0f;
    float g = 0.0f;
    for (int b = 0; b < 8; ++b) g = (g + acc[1 + b]) * (1.0f / 512.0f);
    g *= 0.125f;  // / b
    out[0] = gl + g + g;
  }
}

extern "C" void kernel_launch(void* const* d_in, const int* in_sizes, int n_in,
                              void* d_out, int out_size, void* d_ws, size_t ws_size,
                              hipStream_t stream) {
  (void)in_sizes; (void)n_in; (void)out_size; (void)ws_size;
  const float* logits  = (const float*)d_in[0];
  const float* logits1 = (const float*)d_in[1];
  const float* p0first = (const float*)d_in[2];
  const float* p0sec   = (const float*)d_in[3];
  float* out = (float*)d_out;

  float* acc = (float*)d_ws;                 // [0]=cosSum, [1..8]=S[b]
  int* idxbuf = (int*)d_ws + 16;             // [2*8*512]
  int* knnbuf = idxbuf + 2 * NB * DS;        // [2*8*512*32]

  zero_kernel<<<1, 64, 0, stream>>>(acc);
  fps_cos_kernel<<<80, 1024, 0, stream>>>(logits, logits1, p0first, p0sec, idxbuf, acc);
  knn_kernel<<<2 * NB * DS, 256, 0, stream>>>(p0first, p0sec, idxbuf, knnbuf);
  group_kernel<<<2 * NB * DS / 4, 256, 0, stream>>>(logits, logits1, idxbuf, knnbuf, acc);
  finalize_kernel<<<1, 64, 0, stream>>>(acc, out);
}

// Round 2
// 1014.320 us; speedup vs baseline: 1.4076x; 1.4076x over previous
//
#include <hip/hip_runtime.h>
#include <cstdint>

#define NPTS 8192
#define NB 8
#define DS 512
#define CF 64
#define KNN 32

// ---- DPP wave-64 reductions (VALU only, no DS pipe) ----------------------
// row_shr:1/2/4/8 then row_bcast15 row_bcast31; full reduction lands in lane 63,
// broadcast back via readlane. bound_ctrl=1 (0-fill) => identity 0 is fine for
// sum and for max of non-negative values.
__device__ __forceinline__ float wave_max_bcast(float x) {
  int v;
  v = __builtin_amdgcn_update_dpp(0, __float_as_int(x), 0x111, 0xf, 0xf, true); x = fmaxf(x, __int_as_float(v));
  v = __builtin_amdgcn_update_dpp(0, __float_as_int(x), 0x112, 0xf, 0xf, true); x = fmaxf(x, __int_as_float(v));
  v = __builtin_amdgcn_update_dpp(0, __float_as_int(x), 0x114, 0xf, 0xf, true); x = fmaxf(x, __int_as_float(v));
  v = __builtin_amdgcn_update_dpp(0, __float_as_int(x), 0x118, 0xf, 0xf, true); x = fmaxf(x, __int_as_float(v));
  v = __builtin_amdgcn_update_dpp(0, __float_as_int(x), 0x142, 0xf, 0xf, true); x = fmaxf(x, __int_as_float(v));
  v = __builtin_amdgcn_update_dpp(0, __float_as_int(x), 0x143, 0xf, 0xf, true); x = fmaxf(x, __int_as_float(v));
  return __int_as_float(__builtin_amdgcn_readlane(__float_as_int(x), 63));
}

__device__ __forceinline__ float wave_sum_bcast(float x) {
  int v;
  v = __builtin_amdgcn_update_dpp(0, __float_as_int(x), 0x111, 0xf, 0xf, true); x += __int_as_float(v);
  v = __builtin_amdgcn_update_dpp(0, __float_as_int(x), 0x112, 0xf, 0xf, true); x += __int_as_float(v);
  v = __builtin_amdgcn_update_dpp(0, __float_as_int(x), 0x114, 0xf, 0xf, true); x += __int_as_float(v);
  v = __builtin_amdgcn_update_dpp(0, __float_as_int(x), 0x118, 0xf, 0xf, true); x += __int_as_float(v);
  v = __builtin_amdgcn_update_dpp(0, __float_as_int(x), 0x142, 0xf, 0xf, true); x += __int_as_float(v);
  v = __builtin_amdgcn_update_dpp(0, __float_as_int(x), 0x143, 0xf, 0xf, true); x += __int_as_float(v);
  return __int_as_float(__builtin_amdgcn_readlane(__float_as_int(x), 63));
}

__global__ __launch_bounds__(64) void zero_kernel(float* __restrict__ acc) {
  if (threadIdx.x < 16) acc[threadIdx.x] = 0.0f;
}

// blocks 0..15: FPS (view=blk>>3, batch=blk&7). blocks 16..143: global cosine.
__global__ __launch_bounds__(512) void fps_cos_kernel(
    const float* __restrict__ logits, const float* __restrict__ logits1,
    const float* __restrict__ p0first, const float* __restrict__ p0sec,
    int* __restrict__ idxbuf, float* __restrict__ acc) {
  __shared__ unsigned long long winkey[3];  // triple-buffered packed argmax key
  __shared__ float s_sum;
  const int blk = blockIdx.x;
  const int t = threadIdx.x;
  if (blk < 16) {
    const int view = blk >> 3, b = blk & 7;
    const float* p = (view ? p0sec : p0first) + (size_t)b * NPTS * 3;
    int* idx_out = idxbuf + blk * DS;
    float px[16], py[16], pz[16], dist[16];
#pragma unroll
    for (int j = 0; j < 16; ++j) {
      int e = j * 512 + t;
      px[j] = p[e * 3 + 0];
      py[j] = p[e * 3 + 1];
      pz[j] = p[e * 3 + 2];
      dist[j] = 3.4e38f;
    }
    if (t == 0) {
      idx_out[0] = 0;
      winkey[0] = 0ull; winkey[1] = 0ull; winkey[2] = 0ull;
    }
    float wx = p[0], wy = p[1], wz = p[2];  // seed = point 0
    __syncthreads();
    for (int it = 0; it < DS - 1; ++it) {
      // update min-dists with current center; track value-only local max
      float lm = -1.0f;
#pragma unroll
      for (int j = 0; j < 16; ++j) {
        float dx = px[j] - wx, dy = py[j] - wy, dz = pz[j] - wz;
        float nd = dx * dx + dy * dy + dz * dz;
        float d = fminf(dist[j], nd);
        dist[j] = d;
        lm = fmaxf(lm, d);
      }
      float m = wave_max_bcast(lm);  // VALU-only wave max, broadcast
      if (lm == m) {
        // this thread holds the wave max; smallest local j wins (=> smallest e)
        int jm = 0;
#pragma unroll
        for (int j = 15; j >= 0; --j)
          if (dist[j] == lm) jm = j;
        unsigned e = (unsigned)(jm * 512 + t);
        // key: larger dist wins; ties -> smaller element index (jnp.argmax)
        unsigned long long key =
            (((unsigned long long)__float_as_uint(lm)) << 32) | (8191u - e);
        atomicMax(&winkey[it % 3], key);
      }
      if (t == 0) winkey[(it + 1) % 3] = 0ull;  // reset slot 2 barriers away
      __syncthreads();
      unsigned long long k = winkey[it % 3];
      unsigned e = 8191u - (unsigned)(k & 0xffffffffu);
      if (t == 0) idx_out[it + 1] = (int)e;
      // uniform-address reload of winner coords (L2-hit broadcast)
      wx = p[e * 3 + 0]; wy = p[e * 3 + 1]; wz = p[e * 3 + 2];
    }
  } else {
    // global per-point cosine loss: one thread per row of 64
    if (t == 0) s_sum = 0.0f;
    __syncthreads();
    const int row = (blk - 16) * 512 + t;  // 0..65535
    const float4* A = (const float4*)(logits + (size_t)row * CF);
    const float4* Bv = (const float4*)(logits1 + (size_t)row * CF);
    float ab = 0.f, aa = 0.f, bb = 0.f;
#pragma unroll
    for (int i = 0; i < 16; ++i) {
      float4 a = A[i], c = Bv[i];
      ab += a.x * c.x + a.y * c.y + a.z * c.z + a.w * c.w;
      aa += a.x * a.x + a.y * a.y + a.z * a.z + a.w * a.w;
      bb += c.x * c.x + c.y * c.y + c.z * c.z + c.w * c.w;
    }
    float cv = ab / fmaxf(sqrtf(aa) * sqrtf(bb), 1e-8f);
    cv = wave_sum_bcast(cv);
    if ((t & 63) == 0) atomicAdd(&s_sum, cv);
    __syncthreads();
    if (t == 0) atomicAdd(&acc[0], s_sum);
  }
}

// scan 256-bin LDS histogram, pick bin containing rrank; s_bl[0]=bin, s_bl[1]=count below bin
__device__ __forceinline__ void radix_scan(int* hist, int rrank, int* s_bl, int t) {
  if (t < 64) {
    int h0 = hist[t * 4 + 0], h1 = hist[t * 4 + 1], h2 = hist[t * 4 + 2], h3 = hist[t * 4 + 3];
    int s = h0 + h1 + h2 + h3;
    int inc = s;
#pragma unroll
    for (int o = 1; o < 64; o <<= 1) {
      int v = __shfl_up(inc, o, 64);
      if (t >= o) inc += v;
    }
    int exc = inc - s;
    bool has = (rrank >= exc) && (rrank < inc);
    unsigned long long mask = __ballot(has);
    int win = __ffsll(mask) - 1;
    int wexc = __shfl(exc, win, 64);
    int wh0 = __shfl(h0, win, 64), wh1 = __shfl(h1, win, 64);
    int wh2 = __shfl(h2, win, 64), wh3 = __shfl(h3, win, 64);
    (void)wh3;
    int r2 = rrank - wexc;
    int bin, less;
    if (r2 < wh0) { bin = 0; less = 0; }
    else if (r2 < wh0 + wh1) { bin = 1; less = wh0; }
    else if (r2 < wh0 + wh1 + wh2) { bin = 2; less = wh0 + wh1; }
    else { bin = 3; less = wh0 + wh1 + wh2; }
    if (t == 0) { s_bl[0] = win * 4 + bin; s_bl[1] = wexc + less; }
  }
  __syncthreads();
}

// one block (256 thr) per query; exact top-32 set via 4-pass radix select on sortable keys
__global__ __launch_bounds__(256) void knn_kernel(
    const float* __restrict__ p0first, const float* __restrict__ p0sec,
    const int* __restrict__ idxbuf, int* __restrict__ knnbuf) {
  __shared__ int hist[256];
  __shared__ int s_bl[2];
  __shared__ int ctr, eqctr;
  __shared__ int eq[256];
  const int g = blockIdx.x;  // 0..8191 : view*4096 + b*512 + m
  const int t = threadIdx.x;
  const int view = g >> 12, b = (g >> 9) & 7;
  const float* p = (view ? p0sec : p0first) + (size_t)b * NPTS * 3;
  const int qi = idxbuf[g];
  const float qx = p[qi * 3], qy = p[qi * 3 + 1], qz = p[qi * 3 + 2];
  const float qq = qx * qx + qy * qy + qz * qz;
  unsigned sk[32];
#pragma unroll
  for (int j = 0; j < 32; ++j) {
    int e = j * 256 + t;
    float sx = p[e * 3], sy = p[e * 3 + 1], sz = p[e * 3 + 2];
    float ss = sx * sx + sy * sy + sz * sz;
    float dt = qx * sx + qy * sy + qz * sz;
    float d = qq + ss - 2.0f * dt;  // same formula as reference
    unsigned u = __float_as_uint(d);
    u = (u & 0x80000000u) ? ~u : (u | 0x80000000u);  // sortable
    sk[j] = u;
  }
  int rrank = 31;  // 0-indexed rank of 32nd smallest
  unsigned prefix = 0;
  // pass 0
  hist[t] = 0;
  __syncthreads();
#pragma unroll
  for (int j = 0; j < 32; ++j) atomicAdd(&hist[sk[j] >> 24], 1);
  __syncthreads();
  radix_scan(hist, rrank, s_bl, t);
  prefix = (unsigned)s_bl[0];
  rrank -= s_bl[1];
  // passes 1..3
  for (int pass = 1; pass < 4; ++pass) {
    const int shift = 24 - pass * 8;
    hist[t] = 0;
    __syncthreads();
#pragma unroll
    for (int j = 0; j < 32; ++j) {
      unsigned u = sk[j];
      if ((u >> (shift + 8)) == prefix) atomicAdd(&hist[(u >> shift) & 255], 1);
    }
    __syncthreads();
    radix_scan(hist, rrank, s_bl, t);
    prefix = (prefix << 8) | (unsigned)s_bl[0];
    rrank -= s_bl[1];
  }
  // output: all keys < V, plus (rrank+1) smallest-index keys == V. Order irrelevant.
  if (t == 0) { ctr = 0; eqctr = 0; }
  __syncthreads();
  const unsigned V = prefix;
  int* out = knnbuf + (size_t)g * KNN;
#pragma unroll
  for (int j = 0; j < 32; ++j) {
    unsigned u = sk[j];
    if (u < V) {
      int s = atomicAdd(&ctr, 1);
      out[s] = j * 256 + t;
    } else if (u == V) {
      int s2 = atomicAdd(&eqctr, 1);
      if (s2 < 256) eq[s2] = j * 256 + t;
    }
  }
  __syncthreads();
  if (t == 0) {
    int need = rrank + 1;
    int E = eqctr; if (E > 256) E = 256;
    int base = 32 - need;
    for (int s = 0; s < need; ++s) {
      int mi = 0;
      for (int i = 1; i < E; ++i)
        if (eq[i] < eq[mi]) mi = i;
      out[base + s] = eq[mi];
      eq[mi] = 0x7fffffff;
    }
  }
}

// one wave per group (lane = feature dim); 4 groups per block; DPP reductions
__global__ __launch_bounds__(256) void group_kernel(
    const float* __restrict__ logits, const float* __restrict__ logits1,
    const int* __restrict__ idxbuf, const int* __restrict__ knnbuf,
    float* __restrict__ acc) {
  __shared__ float ws4[4];
  const int w = threadIdx.x >> 6, lane = threadIdx.x & 63;
  const int wid = blockIdx.x * 4 + w;  // 0..8191
  const int view = wid >> 12, b = (wid >> 9) & 7;
  const float* f = (view ? logits1 : logits) + (size_t)b * NPTS * CF;
  const int* nb = knnbuf + (size_t)wid * KNN;
  const int ci = idxbuf[wid];
  float r[33];
  float avg = 0.0f;
#pragma unroll
  for (int j = 0; j < 33; ++j) {
    int e = (j < 32) ? nb[j] : ci;
    float v = f[(size_t)e * CF + lane];
    r[j] = v;
    avg += v;
  }
  avg *= (1.0f / 33.0f);
  float na = wave_sum_bcast(avg * avg);
  const float rsna = sqrtf(na);
  float loss = 0.0f;
#pragma unroll
  for (int j = 0; j < 33; ++j) {
    float d0 = wave_sum_bcast(r[j] * avg);
    float n0 = wave_sum_bcast(r[j] * r[j]);
    float den = fmaxf(sqrtf(n0) * rsna, 1e-8f);
    loss += -200.0f * (d0 / den) - 0.5f * log1pf(40.0f * n0);
  }
  loss *= (1.0f / 33.0f);
  if (lane == 0) ws4[w] = loss;
  __syncthreads();
  if (threadIdx.x == 0) atomicAdd(&acc[1 + b], ws4[0] + ws4[1] + ws4[2] + ws4[3]);
}

__global__ __launch_bounds__(64) void finalize_kernel(const float* __restrict__ acc,
                                                      float* __restrict__ out) {
  if (threadIdx.x == 0 && blockIdx.x == 0) {
    float gl = -acc[0] / 65536.0f;
    float g = 0.0f;
    for (int b = 0; b < 8; ++b) g = (g + acc[1 + b]) * (1.0f / 512.0f);
    g *= 0.125f;  // / b
    out[0] = gl + g + g;
  }
}

extern "C" void kernel_launch(void* const* d_in, const int* in_sizes, int n_in,
                              void* d_out, int out_size, void* d_ws, size_t ws_size,
                              hipStream_t stream) {
  (void)in_sizes; (void)n_in; (void)out_size; (void)ws_size;
  const float* logits  = (const float*)d_in[0];
  const float* logits1 = (const float*)d_in[1];
  const float* p0first = (const float*)d_in[2];
  const float* p0sec   = (const float*)d_in[3];
  float* out = (float*)d_out;

  float* acc = (float*)d_ws;                 // [0]=cosSum, [1..8]=S[b]
  int* idxbuf = (int*)d_ws + 16;             // [2*8*512]
  int* knnbuf = idxbuf + 2 * NB * DS;        // [2*8*512*32]

  zero_kernel<<<1, 64, 0, stream>>>(acc);
  fps_cos_kernel<<<16 + 128, 512, 0, stream>>>(logits, logits1, p0first, p0sec, idxbuf, acc);
  knn_kernel<<<2 * NB * DS, 256, 0, stream>>>(p0first, p0sec, idxbuf, knnbuf);
  group_kernel<<<2 * NB * DS / 4, 256, 0, stream>>>(logits, logits1, idxbuf, knnbuf, acc);
  finalize_kernel<<<1, 64, 0, stream>>>(acc, out);
}